// Round 8
// baseline (357.366 us; speedup 1.0000x reference)
//
#include <hip/hip_runtime.h>
#include <cmath>

#define SEQ 2048
#define DM 512
#define DFF 2048
#define NH 8
#define DKH 64
#define NROWS 8192  // B*S = 4*2048

typedef __attribute__((ext_vector_type(8))) short bf16x8;
typedef __attribute__((ext_vector_type(16))) float f32x16;

__device__ __forceinline__ ushort f2bf(float f) {
    uint u = __float_as_uint(f);
    u += 0x7fff + ((u >> 16) & 1);
    return (ushort)(u >> 16);
}
__device__ __forceinline__ float bf2f(ushort h) {
    return __uint_as_float(((uint)h) << 16);
}
__device__ __forceinline__ uint cvtpk_bf16(float a, float b) {
    uint r;
    asm("v_cvt_pk_bf16_f32 %0, %1, %2" : "=v"(r) : "v"(a), "v"(b));
    return r;
}
// async global->LDS, 16B per lane. LDS dest = base + lane*16 (linear).
__device__ __forceinline__ void gl_lds16(const void* g, void* l) {
    __builtin_amdgcn_global_load_lds(
        (const __attribute__((address_space(1))) void*)g,
        (__attribute__((address_space(3))) void*)l, 16, 0, 0);
}
// 128B-row LDS swizzle (attn): byte ^= (row&7)<<4
__device__ __forceinline__ void* swz(char* base, int row, int col) {
    int byte = (row << 7) + (col << 1);
    byte ^= (row & 7) << 4;
    return base + byte;
}
// gemm LDS swizzle: byte ^= ((row>>2)&7)<<4
__device__ __forceinline__ void* swzg(char* base, int row, int k) {
    int byte = (row << 7) + (k << 1);
    byte ^= ((row >> 2) & 7) << 4;
    return base + byte;
}

// ---------------------------------------------------------------------------
// LayerNorm -> bf16 (hi, optional lo)
// ---------------------------------------------------------------------------
template<bool SPLIT>
__global__ __launch_bounds__(64) void ln_kernel(const float* __restrict__ x,
        const float* __restrict__ g, const float* __restrict__ b,
        ushort* __restrict__ oh, ushort* __restrict__ ol) {
    int row = blockIdx.x;
    int t = threadIdx.x;
    const float* xr = x + (size_t)row * DM + t * 8;
    float v[8];
    *(float4*)&v[0] = *(const float4*)(xr);
    *(float4*)&v[4] = *(const float4*)(xr + 4);
    float s = 0.f;
    #pragma unroll
    for (int j = 0; j < 8; ++j) s += v[j];
    #pragma unroll
    for (int m = 32; m > 0; m >>= 1) s += __shfl_xor(s, m);
    float mean = s * (1.0f / DM);
    float ss = 0.f;
    #pragma unroll
    for (int j = 0; j < 8; ++j) { float d = v[j] - mean; ss += d * d; }
    #pragma unroll
    for (int m = 32; m > 0; m >>= 1) ss += __shfl_xor(ss, m);
    float inv = 1.0f / (sqrtf(ss * (1.0f / (DM - 1))) + 1e-6f);
    float gv[8], bv[8];
    *(float4*)&gv[0] = *(const float4*)(g + t * 8);
    *(float4*)&gv[4] = *(const float4*)(g + t * 8 + 4);
    *(float4*)&bv[0] = *(const float4*)(b + t * 8);
    *(float4*)&bv[4] = *(const float4*)(b + t * 8 + 4);
    union { ushort us[8]; float4 f4; } ph, pl;
    #pragma unroll
    for (int j = 0; j < 8; ++j) {
        float o = gv[j] * (v[j] - mean) * inv + bv[j];
        ushort hb = f2bf(o);
        ph.us[j] = hb;
        if (SPLIT) pl.us[j] = f2bf(o - bf2f(hb));
    }
    *(float4*)(oh + (size_t)row * DM + t * 8) = ph.f4;
    if (SPLIT) *(float4*)(ol + (size_t)row * DM + t * 8) = pl.f4;
}

// ---------------------------------------------------------------------------
// Merged weight transpose+convert for the four 512x512 weights.
// ---------------------------------------------------------------------------
__global__ __launch_bounds__(256) void wconv4(
        const float* __restrict__ wq, const float* __restrict__ wk,
        const float* __restrict__ wv, const float* __restrict__ wo,
        ushort* __restrict__ qh, ushort* __restrict__ ql,
        ushort* __restrict__ kh, ushort* __restrict__ kl,
        ushort* __restrict__ vh, ushort* __restrict__ oh) {
    const int K = DM, N = DM;
    __shared__ float tile[64][65];
    int z = blockIdx.z;
    const float* W = (z == 0) ? wq : (z == 1) ? wk : (z == 2) ? wv : wo;
    ushort* Th = (z == 0) ? qh : (z == 1) ? kh : (z == 2) ? vh : oh;
    ushort* Tl = (z == 0) ? ql : (z == 1) ? kl : nullptr;
    bool split = (z < 2);
    int k0 = blockIdx.x * 64, n0 = blockIdx.y * 64;
    int t = threadIdx.x;
    {
        int kr = t >> 2, c0 = (t & 3) * 16;
        const float* src = W + (size_t)(k0 + kr) * N + n0 + c0;
        #pragma unroll
        for (int j = 0; j < 4; ++j)
            *(float4*)&tile[kr][c0 + j * 4] = *(const float4*)(src + j * 4);
    }
    __syncthreads();
    int n = t >> 2, kc = (t & 3) * 16;
    union { ushort us[16]; float4 f4[2]; } ph, pl;
    #pragma unroll
    for (int j = 0; j < 16; ++j) {
        float v = tile[kc + j][n];
        ushort hb = f2bf(v);
        ph.us[j] = hb;
        pl.us[j] = f2bf(v - bf2f(hb));
    }
    ushort* dh = Th + (size_t)(n0 + n) * K + k0 + kc;
    *(float4*)(dh) = ph.f4[0];
    *(float4*)(dh + 8) = ph.f4[1];
    if (split) {
        ushort* dl = Tl + (size_t)(n0 + n) * K + k0 + kc;
        *(float4*)(dl) = pl.f4[0];
        *(float4*)(dl + 8) = pl.f4[1];
    }
}

// ---------------------------------------------------------------------------
// Weight transpose+convert (single, for w1/w2)
// ---------------------------------------------------------------------------
__global__ __launch_bounds__(256) void wconv(const float* __restrict__ W,
        ushort* __restrict__ Th, int K, int N) {
    __shared__ float tile[64][65];
    int k0 = blockIdx.x * 64, n0 = blockIdx.y * 64;
    int t = threadIdx.x;
    {
        int kr = t >> 2, c0 = (t & 3) * 16;
        const float* src = W + (size_t)(k0 + kr) * N + n0 + c0;
        #pragma unroll
        for (int j = 0; j < 4; ++j)
            *(float4*)&tile[kr][c0 + j * 4] = *(const float4*)(src + j * 4);
    }
    __syncthreads();
    int n = t >> 2, kc = (t & 3) * 16;
    union { ushort us[16]; float4 f4[2]; } ph;
    #pragma unroll
    for (int j = 0; j < 16; ++j) ph.us[j] = f2bf(tile[kc + j][n]);
    ushort* dh = Th + (size_t)(n0 + n) * K + k0 + kc;
    *(float4*)(dh) = ph.f4[0];
    *(float4*)(dh + 8) = ph.f4[1];
}

// ---------------------------------------------------------------------------
// V transpose: vh[(b*SEQ+s)][DM] bf16 (head h cols) -> vt[(bh*64+d)][SEQ] bf16
// ---------------------------------------------------------------------------
__global__ __launch_bounds__(256) void vtrans(const ushort* __restrict__ vh,
        ushort* __restrict__ vt) {
    __shared__ __align__(16) char tile[8192];
    int s0 = blockIdx.x * 64;
    int bh = blockIdx.y;
    int b = bh >> 3, h = bh & 7;
    int t = threadIdx.x;
    {
        int r = t >> 2, co = (t & 3) * 16;
        const ushort* src = vh + (size_t)(b * SEQ + s0 + r) * DM + h * DKH + co;
        *(float4*)swz(tile, r, co) = *(const float4*)(src);
        *(float4*)swz(tile, r, co + 8) = *(const float4*)(src + 8);
    }
    __syncthreads();
    int d = t >> 2, j0 = (t & 3) * 16;
    union { ushort us[16]; float4 f4[2]; } o;
    #pragma unroll
    for (int j = 0; j < 16; ++j)
        o.us[j] = *(ushort*)swz(tile, j0 + j, d);
    ushort* dst = vt + ((size_t)bh * DKH + d) * SEQ + s0 + j0;
    *(float4*)(dst) = o.f4[0];
    *(float4*)(dst + 8) = o.f4[1];
}

// ---------------------------------------------------------------------------
// Mask -> additive bf16 bias {0,-1e9} + per-(row, 64-key-tile) all-ones flags.
// ---------------------------------------------------------------------------
__global__ __launch_bounds__(64) void maskprep(const int* __restrict__ mask,
        ushort* __restrict__ mb, unsigned char* __restrict__ mflag) {
    int row = blockIdx.x;
    int lane = threadIdx.x;
    ushort neg = f2bf(-1e9f);
    unsigned long long bal[4];
    #pragma unroll
    for (int u = 0; u < 4; ++u) {
        int base = row * SEQ + u * 512 + lane * 8;
        int4 a = *(const int4*)(mask + base);
        int4 c = *(const int4*)(mask + base + 4);
        union { ushort us[8]; float4 f4; } o;
        o.us[0] = a.x ? (ushort)0 : neg;
        o.us[1] = a.y ? (ushort)0 : neg;
        o.us[2] = a.z ? (ushort)0 : neg;
        o.us[3] = a.w ? (ushort)0 : neg;
        o.us[4] = c.x ? (ushort)0 : neg;
        o.us[5] = c.y ? (ushort)0 : neg;
        o.us[6] = c.z ? (ushort)0 : neg;
        o.us[7] = c.w ? (ushort)0 : neg;
        *(float4*)(mb + base) = o.f4;
        bool ok = a.x && a.y && a.z && a.w && c.x && c.y && c.z && c.w;
        bal[u] = __ballot(ok);
    }
    if (lane < 32) {
        int u = lane >> 3;
        unsigned long long bsel = bal[0];
        bsel = (u == 1) ? bal[1] : bsel;
        bsel = (u == 2) ? bal[2] : bsel;
        bsel = (u == 3) ? bal[3] : bsel;
        int byte = (int)((bsel >> ((lane & 7) * 8)) & 0xFFull);
        mflag[row * 32 + lane] = (byte == 0xFF) ? 1 : 0;
    }
}

// ---------------------------------------------------------------------------
// 1-term MFMA GEMM, double-buffered via global_load_lds prefetch.
// ---------------------------------------------------------------------------
template<bool RELU, bool HASRES, int OUT>
__global__ __launch_bounds__(256) void mgemm(
        const ushort* __restrict__ Ah, const ushort* __restrict__ Bth,
        const float* __restrict__ bias, const float* __restrict__ resid,
        float* __restrict__ Cf, ushort* __restrict__ Cbh,
        int M, int N, int K) {
    __shared__ __align__(16) char smem[65536];
    int tid = threadIdx.x;
    int lane = tid & 63, w = tid >> 6;
    int ln31 = lane & 31, hi = lane >> 5;
    int mh = (w >> 1) * 64, nh = (w & 1) * 64;
    int gx = gridDim.x;
    int nwg = gx * gridDim.y;
    int flat = blockIdx.y * gx + blockIdx.x;
    int sid = (flat & 7) * (nwg >> 3) + (flat >> 3);
    int n0 = (sid % gx) * 128;
    int m0 = (sid / gx) * 128;

    f32x16 acc[2][2];
    #pragma unroll
    for (int i = 0; i < 2; ++i)
        #pragma unroll
        for (int j = 0; j < 2; ++j)
            #pragma unroll
            for (int r = 0; r < 16; ++r) acc[i][j][r] = 0.f;

    auto stage = [&](char* Abuf, char* Bbuf, int k0) {
        #pragma unroll
        for (int c = 0; c < 4; ++c) {
            int ch = w * 4 + c;
            int r = ch * 8 + (lane >> 3);
            int u = (lane & 7) ^ ((r >> 2) & 7);
            gl_lds16(Ah + (size_t)(m0 + r) * K + k0 + u * 8, Abuf + ch * 1024);
            gl_lds16(Bth + (size_t)(n0 + r) * K + k0 + u * 8, Bbuf + ch * 1024);
        }
    };

    char* A0 = smem;
    char* B0 = smem + 16384;
    char* A1 = smem + 32768;
    char* B1 = smem + 49152;

    stage(A0, B0, 0);
    __syncthreads();
    int nk = K / 64;
    for (int kt = 0; kt < nk; ++kt) {
        char* Ac = (kt & 1) ? A1 : A0;
        char* Bc = (kt & 1) ? B1 : B0;
        if (kt + 1 < nk)
            stage((kt & 1) ? A0 : A1, (kt & 1) ? B0 : B1, (kt + 1) * 64);
        __builtin_amdgcn_s_setprio(1);
        #pragma unroll
        for (int km = 0; km < 4; ++km) {
            int kk = km * 16 + hi * 8;
            bf16x8 ah[2], bh[2];
            ah[0] = *(bf16x8*)swzg(Ac, mh + ln31, kk);
            ah[1] = *(bf16x8*)swzg(Ac, mh + 32 + ln31, kk);
            bh[0] = *(bf16x8*)swzg(Bc, nh + ln31, kk);
            bh[1] = *(bf16x8*)swzg(Bc, nh + 32 + ln31, kk);
            #pragma unroll
            for (int mi = 0; mi < 2; ++mi)
                #pragma unroll
                for (int ni = 0; ni < 2; ++ni)
                    acc[mi][ni] = __builtin_amdgcn_mfma_f32_32x32x16_bf16(
                        ah[mi], bh[ni], acc[mi][ni], 0, 0, 0);
        }
        __builtin_amdgcn_s_setprio(0);
        __syncthreads();
    }
    float bv[2];
    bv[0] = bias[n0 + nh + ln31];
    bv[1] = bias[n0 + nh + 32 + ln31];
    #pragma unroll
    for (int mi = 0; mi < 2; ++mi)
        #pragma unroll
        for (int ni = 0; ni < 2; ++ni) {
            int n = n0 + nh + ni * 32 + ln31;
            #pragma unroll
            for (int r = 0; r < 16; ++r) {
                int m = m0 + mh + mi * 32 + (r & 3) + 8 * (r >> 2) + 4 * hi;
                float v = acc[mi][ni][r] + bv[ni];
                if (HASRES) v += resid[(size_t)m * N + n];
                if (RELU) v = fmaxf(v, 0.f);
                size_t idx = (size_t)m * N + n;
                if (OUT == 0) Cf[idx] = v;
                else Cbh[idx] = f2bf(v);
            }
        }
}

// ---------------------------------------------------------------------------
// Fused QKV GEMM. Q output pre-scaled by 1/8 (exact exponent shift) so the
// attention kernel can floor() the MFMA result directly.
// ---------------------------------------------------------------------------
__global__ __launch_bounds__(256) void qkv_gemm(
        const ushort* __restrict__ Ah, const ushort* __restrict__ Al,
        const ushort* __restrict__ Bth, const ushort* __restrict__ Btl,
        const float* __restrict__ bq, const float* __restrict__ bk,
        const float* __restrict__ bv_, ushort* __restrict__ q_h,
        ushort* __restrict__ q_l, ushort* __restrict__ k_h,
        ushort* __restrict__ k_l, ushort* __restrict__ v_h) {
    const int K = DM, N = DM;
    __shared__ __align__(16) char smem[65536];
    char* As_h = smem;
    char* Bs_h = smem + 16384;
    char* As_l = smem + 32768;
    char* Bs_l = smem + 49152;
    int tid = threadIdx.x;
    int lane = tid & 63, w = tid >> 6;
    int ln31 = lane & 31, hi = lane >> 5;
    int mh = (w >> 1) * 64, nh = (w & 1) * 64;
    int gx = gridDim.x;  // 12
    int nwg = gx * gridDim.y;
    int flat = blockIdx.y * gx + blockIdx.x;
    int sid = (flat & 7) * (nwg >> 3) + (flat >> 3);
    int n0 = (sid % gx) * 128;
    int m0 = (sid / gx) * 128;
    bool isqk = (n0 < 1024);

    f32x16 acc[2][2];
    #pragma unroll
    for (int i = 0; i < 2; ++i)
        #pragma unroll
        for (int j = 0; j < 2; ++j)
            #pragma unroll
            for (int r = 0; r < 16; ++r) acc[i][j][r] = 0.f;

    for (int k0 = 0; k0 < K; k0 += 64) {
        #pragma unroll
        for (int c = 0; c < 4; ++c) {
            int ch = w * 4 + c;
            int r = ch * 8 + (lane >> 3);
            int u = (lane & 7) ^ ((r >> 2) & 7);
            gl_lds16(Ah + (size_t)(m0 + r) * K + k0 + u * 8, As_h + ch * 1024);
            gl_lds16(Bth + (size_t)(n0 + r) * K + k0 + u * 8, Bs_h + ch * 1024);
            if (isqk) {
                gl_lds16(Al + (size_t)(m0 + r) * K + k0 + u * 8, As_l + ch * 1024);
                gl_lds16(Btl + (size_t)(n0 + r) * K + k0 + u * 8, Bs_l + ch * 1024);
            }
        }
        __syncthreads();
        __builtin_amdgcn_s_setprio(1);
        #pragma unroll
        for (int km = 0; km < 4; ++km) {
            int kk = km * 16 + hi * 8;
            bf16x8 ah[2], bh[2];
            ah[0] = *(bf16x8*)swzg(As_h, mh + ln31, kk);
            ah[1] = *(bf16x8*)swzg(As_h, mh + 32 + ln31, kk);
            bh[0] = *(bf16x8*)swzg(Bs_h, nh + ln31, kk);
            bh[1] = *(bf16x8*)swzg(Bs_h, nh + 32 + ln31, kk);
            if (isqk) {
                bf16x8 al[2], bl[2];
                al[0] = *(bf16x8*)swzg(As_l, mh + ln31, kk);
                al[1] = *(bf16x8*)swzg(As_l, mh + 32 + ln31, kk);
                bl[0] = *(bf16x8*)swzg(Bs_l, nh + ln31, kk);
                bl[1] = *(bf16x8*)swzg(Bs_l, nh + 32 + ln31, kk);
                #pragma unroll
                for (int mi = 0; mi < 2; ++mi)
                    #pragma unroll
                    for (int ni = 0; ni < 2; ++ni) {
                        acc[mi][ni] = __builtin_amdgcn_mfma_f32_32x32x16_bf16(
                            ah[mi], bh[ni], acc[mi][ni], 0, 0, 0);
                        acc[mi][ni] = __builtin_amdgcn_mfma_f32_32x32x16_bf16(
                            ah[mi], bl[ni], acc[mi][ni], 0, 0, 0);
                        acc[mi][ni] = __builtin_amdgcn_mfma_f32_32x32x16_bf16(
                            al[mi], bh[ni], acc[mi][ni], 0, 0, 0);
                    }
            } else {
                #pragma unroll
                for (int mi = 0; mi < 2; ++mi)
                    #pragma unroll
                    for (int ni = 0; ni < 2; ++ni)
                        acc[mi][ni] = __builtin_amdgcn_mfma_f32_32x32x16_bf16(
                            ah[mi], bh[ni], acc[mi][ni], 0, 0, 0);
            }
        }
        __builtin_amdgcn_s_setprio(0);
        __syncthreads();
    }
    const float* bias = (n0 < 512) ? bq : (n0 < 1024 ? bk : bv_);
    int ncol0 = n0 & 511;
    ushort* Oh = (n0 < 512) ? q_h : (n0 < 1024 ? k_h : v_h);
    ushort* Ol = (n0 < 512) ? q_l : (n0 < 1024 ? k_l : nullptr);
    float scale = (n0 < 512) ? 0.125f : 1.0f;
    float bvv[2];
    bvv[0] = bias[ncol0 + nh + ln31];
    bvv[1] = bias[ncol0 + nh + 32 + ln31];
    #pragma unroll
    for (int mi = 0; mi < 2; ++mi)
        #pragma unroll
        for (int ni = 0; ni < 2; ++ni) {
            int n = ncol0 + nh + ni * 32 + ln31;
            #pragma unroll
            for (int r = 0; r < 16; ++r) {
                int m = m0 + mh + mi * 32 + (r & 3) + 8 * (r >> 2) + 4 * hi;
                float v = (acc[mi][ni][r] + bvv[ni]) * scale;
                size_t idx = (size_t)m * N + n;
                ushort hb = f2bf(v);
                Oh[idx] = hb;
                if (isqk) Ol[idx] = f2bf(v - bf2f(hb));
            }
        }
}

// ---------------------------------------------------------------------------
// MFMA flash attention, split-K x2. 40KB LDS (4 blocks/CU): K hi/lo
// double-buffered (32K), V^T single-buffered (8K, re-staged after PV barrier).
// Merged 64-key softmax: one max/psum/rescale per kt-tile.
// ---------------------------------------------------------------------------
__global__ __launch_bounds__(256, 4) void attn_kernel(
        const ushort* __restrict__ Qh, const ushort* __restrict__ Ql,
        const ushort* __restrict__ Khg, const ushort* __restrict__ Klg,
        const ushort* __restrict__ Vtg, const ushort* __restrict__ mb,
        const unsigned char* __restrict__ mflag,
        ushort* __restrict__ pctx0, ushort* __restrict__ pctx1,
        float2* __restrict__ ml) {
    __shared__ __align__(16) char smem[40960];
    // K buf0 @0 (Kh 8K + Kl 8K), K buf1 @16K, Vt @32K (8K)
    int tid = threadIdx.x;
    int w = tid >> 6, lane = tid & 63;
    int ln31 = lane & 31, hi = lane >> 5;
    bool hib = (hi != 0);
    int f = blockIdx.y * gridDim.x + blockIdx.x;
    int g = (f & 7) * 128 + (f >> 3);
    int bh = g >> 5, rest = g & 31;
    int part = rest >> 4, qb = rest & 15;
    int b = bh >> 3, h = bh & 7;
    int q0 = qb * 128;
    size_t brow = (size_t)b * SEQ;
    int hcol = h * DKH;
    int ktbeg = part * 16, ktend = ktbeg + 16;

    auto stage_K = [&](int kt) {
        char* buf = smem + (kt & 1) * 16384;
        #pragma unroll
        for (int c = 0; c < 2; ++c) {
            int ch = w * 2 + c;
            int r = ch * 8 + (lane >> 3);
            int u = (lane & 7) ^ (r & 7);
            gl_lds16(Khg + (brow + kt * 64 + r) * DM + hcol + u * 8,
                     buf + ch * 1024);
            gl_lds16(Klg + (brow + kt * 64 + r) * DM + hcol + u * 8,
                     buf + 8192 + ch * 1024);
        }
    };
    auto stage_V = [&](int kt) {
        char* buf = smem + 32768;
        #pragma unroll
        for (int c = 0; c < 2; ++c) {
            int ch = w * 2 + c;
            int r = ch * 8 + (lane >> 3);
            int u = (lane & 7) ^ (r & 7);
            gl_lds16(Vtg + ((size_t)bh * DKH + r) * SEQ + kt * 64 + u * 8,
                     buf + ch * 1024);
        }
    };

    // prologue: stage Q into smem[0..32K), read frags
    {
        char* QhL = smem;
        char* QlL = smem + 16384;
        #pragma unroll
        for (int c = 0; c < 4; ++c) {
            int ch = w * 4 + c;
            int r = ch * 8 + (lane >> 3);
            int u = (lane & 7) ^ (r & 7);
            gl_lds16(Qh + (brow + q0 + r) * DM + hcol + u * 8, QhL + ch * 1024);
            gl_lds16(Ql + (brow + q0 + r) * DM + hcol + u * 8, QlL + ch * 1024);
        }
    }
    __syncthreads();
    bf16x8 qfh[4], qfl[4];
    {
        int qr = w * 32 + ln31;
        #pragma unroll
        for (int c = 0; c < 4; ++c) {
            qfh[c] = *(bf16x8*)swz(smem, qr, c * 16 + hi * 8);
            qfl[c] = *(bf16x8*)swz(smem + 16384, qr, c * 16 + hi * 8);
        }
    }
    __syncthreads();
    stage_K(ktbeg);
    stage_V(ktbeg);
    __syncthreads();

    f32x16 ctx0, ctx1;
    #pragma unroll
    for (int r = 0; r < 16; ++r) { ctx0[r] = 0.f; ctx1[r] = 0.f; }
    float m_i = -1e30f, l_i = 0.f;
    int qglob = q0 + w * 32 + ln31;
    const ushort* mrow = mb + (size_t)qglob * SEQ;

    for (int kt = ktbeg; kt < ktend; ++kt) {
        if (kt + 1 < ktend) stage_K(kt + 1);
        char* KhL = smem + (kt & 1) * 16384;
        char* KlL = KhL + 8192;
        char* VtL = smem + 32768;
        unsigned char fl = mflag[qglob * 32 + kt];
        bool domask = !__all(fl != 0);

        // ---- QK^T for both 32-key halves (Q pre-scaled by 1/8) ----
        f32x16 s0, s1;
        #pragma unroll
        for (int r = 0; r < 16; ++r) { s0[r] = 0.f; s1[r] = 0.f; }
        __builtin_amdgcn_s_setprio(1);
        #pragma unroll
        for (int c = 0; c < 4; ++c) {
            bf16x8 ka0 = *(bf16x8*)swz(KhL, ln31, c * 16 + hi * 8);
            bf16x8 kb0 = *(bf16x8*)swz(KlL, ln31, c * 16 + hi * 8);
            bf16x8 ka1 = *(bf16x8*)swz(KhL, 32 + ln31, c * 16 + hi * 8);
            bf16x8 kb1 = *(bf16x8*)swz(KlL, 32 + ln31, c * 16 + hi * 8);
            s0 = __builtin_amdgcn_mfma_f32_32x32x16_bf16(ka0, qfh[c], s0, 0, 0, 0);
            s1 = __builtin_amdgcn_mfma_f32_32x32x16_bf16(ka1, qfh[c], s1, 0, 0, 0);
            s0 = __builtin_amdgcn_mfma_f32_32x32x16_bf16(ka0, qfl[c], s0, 0, 0, 0);
            s1 = __builtin_amdgcn_mfma_f32_32x32x16_bf16(ka1, qfl[c], s1, 0, 0, 0);
            s0 = __builtin_amdgcn_mfma_f32_32x32x16_bf16(kb0, qfh[c], s0, 0, 0, 0);
            s1 = __builtin_amdgcn_mfma_f32_32x32x16_bf16(kb1, qfh[c], s1, 0, 0, 0);
        }
        __builtin_amdgcn_s_setprio(0);

        // ---- floor + mask + merged softmax over 64 keys ----
        if (domask) {
            #pragma unroll
            for (int rg = 0; rg < 4; ++rg) {
                ushort4 mv0 = *(const ushort4*)(mrow + kt * 64 + rg * 8 + hi * 4);
                ushort4 mv1 = *(const ushort4*)(mrow + kt * 64 + 32 + rg * 8 + hi * 4);
                ushort mu0[4] = {mv0.x, mv0.y, mv0.z, mv0.w};
                ushort mu1[4] = {mv1.x, mv1.y, mv1.z, mv1.w};
                #pragma unroll
                for (int j = 0; j < 4; ++j) {
                    s0[rg * 4 + j] = floorf(s0[rg * 4 + j]) + bf2f(mu0[j]);
                    s1[rg * 4 + j] = floorf(s1[rg * 4 + j]) + bf2f(mu1[j]);
                }
            }
        } else {
            #pragma unroll
            for (int r = 0; r < 16; ++r) {
                s0[r] = floorf(s0[r]);
                s1[r] = floorf(s1[r]);
            }
        }
        float tmax = -1e30f;
        #pragma unroll
        for (int r = 0; r < 16; ++r)
            tmax = fmaxf(tmax, fmaxf(s0[r], s1[r]));
        tmax = fmaxf(tmax, __shfl_xor(tmax, 32));
        if (!__all(tmax <= m_i)) {
            float newm = fmaxf(m_i, tmax);
            float scl = __expf(m_i - newm);
            m_i = newm;
            l_i *= scl;
            #pragma unroll
            for (int r = 0; r < 16; ++r) { ctx0[r] *= scl; ctx1[r] *= scl; }
        }
        float psum = 0.f;
        #pragma unroll
        for (int r = 0; r < 16; ++r) {
            float p0 = __expf(s0[r] - m_i);
            float p1 = __expf(s1[r] - m_i);
            s0[r] = p0;
            s1[r] = p1;
            psum += p0 + p1;
        }
        psum += __shfl_xor(psum, 32);
        l_i += psum;

        // ---- pack P (both halves) and exchange across hi-halves ----
        bf16x8 pb[4];
        #pragma unroll
        for (int ksub = 0; ksub < 2; ++ksub) {
            uint pk0[4], pk1[4];
            #pragma unroll
            for (int rg = 0; rg < 4; ++rg) {
                const f32x16& sv = ksub ? s1 : s0;
                pk0[rg] = cvtpk_bf16(sv[rg * 4 + 0], sv[rg * 4 + 1]);
                pk1[rg] = cvtpk_bf16(sv[rg * 4 + 2], sv[rg * 4 + 3]);
            }
            #pragma unroll
            for (int cc = 0; cc < 2; ++cc) {
                uint A0 = pk0[cc * 2], A1 = pk1[cc * 2];
                uint B0 = pk0[cc * 2 + 1], B1 = pk1[cc * 2 + 1];
                uint send0 = hib ? A0 : B0;
                uint send1 = hib ? A1 : B1;
                uint own0  = hib ? B0 : A0;
                uint own1  = hib ? B1 : A1;
                uint recv0 = (uint)__shfl_xor((int)send0, 32);
                uint recv1 = (uint)__shfl_xor((int)send1, 32);
                union { uint u[4]; bf16x8 v; } pbu;
                pbu.u[0] = hib ? recv0 : own0;
                pbu.u[1] = hib ? recv1 : own1;
                pbu.u[2] = hib ? own0 : recv0;
                pbu.u[3] = hib ? own1 : recv1;
                pb[ksub * 2 + cc] = pbu.v;
            }
        }

        __syncthreads();  // drains V(kt) + K(kt+1); all waves past K/V reads issue
        __builtin_amdgcn_s_setprio(1);
        #pragma unroll
        for (int c = 0; c < 4; ++c) {
            bf16x8 va0 = *(bf16x8*)swz(VtL, ln31, c * 16 + hi * 8);
            bf16x8 va1 = *(bf16x8*)swz(VtL, 32 + ln31, c * 16 + hi * 8);
            ctx0 = __builtin_amdgcn_mfma_f32_32x32x16_bf16(va0, pb[c], ctx0, 0, 0, 0);
            ctx1 = __builtin_amdgcn_mfma_f32_32x32x16_bf16(va1, pb[c], ctx1, 0, 0, 0);
        }
        __builtin_amdgcn_s_setprio(0);
        __syncthreads();  // all waves done reading Vt
        if (kt + 1 < ktend) stage_V(kt + 1);
    }

    // epilogue: write unnormalized partial ctx (bf16) + (m,l)
    ushort* P = part ? pctx1 : pctx0;
    size_t pbase = ((size_t)bh * SEQ + qglob) * DKH;
    #pragma unroll
    for (int r = 0; r < 16; ++r) {
        int d = (r & 3) + 8 * (r >> 2) + 4 * hi;
        P[pbase + d] = f2bf(ctx0[r]);
        P[pbase + 32 + d] = f2bf(ctx1[r]);
    }
    if (hi == 0)
        ml[((size_t)part * 32 + bh) * SEQ + qglob] = make_float2(m_i, l_i);
}

// ---------------------------------------------------------------------------
// Combine the two split-K partials exactly; write ctx bf16 [b*SEQ+q][DM].
// ---------------------------------------------------------------------------
__global__ __launch_bounds__(256) void attn_combine(
        const ushort* __restrict__ p0, const ushort* __restrict__ p1,
        const float2* __restrict__ ml, ushort* __restrict__ O) {
    int idx = blockIdx.x * 256 + threadIdx.x;
    int d0 = (idx & 7) * 8;
    int q = (idx >> 3) & (SEQ - 1);
    int bh = idx >> 14;
    int b = bh >> 3, h = bh & 7;
    size_t pb = ((size_t)bh * SEQ + q) * DKH + d0;
    bf16x8 c0 = *(const bf16x8*)(p0 + pb);
    bf16x8 c1 = *(const bf16x8*)(p1 + pb);
    float2 e0 = ml[(size_t)bh * SEQ + q];
    float2 e1 = ml[((size_t)32 + bh) * SEQ + q];
    float m = fmaxf(e0.x, e1.x);
    float w0 = __expf(e0.x - m), w1 = __expf(e1.x - m);
    float inv = 1.0f / (e0.y * w0 + e1.y * w1);
    union { ushort us[8]; float4 f4; } o;
    #pragma unroll
    for (int j = 0; j < 8; ++j) {
        float v0 = bf2f((ushort)c0[j]);
        float v1 = bf2f((ushort)c1[j]);
        o.us[j] = f2bf((v0 * w0 + v1 * w1) * inv);
    }
    *(float4*)(O + ((size_t)(b * SEQ + q)) * DM + h * DKH + d0) = o.f4;
}

// ---------------------------------------------------------------------------
extern "C" void kernel_launch(void* const* d_in, const int* in_sizes, int n_in,
                              void* d_out, int out_size, void* d_ws, size_t ws_size,
                              hipStream_t stream) {
    const float* x    = (const float*)d_in[0];
    const int*   mask = (const int*)d_in[1];
    const float* wq = (const float*)d_in[2];
    const float* bq = (const float*)d_in[3];
    const float* wk = (const float*)d_in[4];
    const float* bk = (const float*)d_in[5];
    const float* wv = (const float*)d_in[6];
    const float* bv = (const float*)d_in[7];
    const float* wo = (const float*)d_in[8];
    const float* bo = (const float*)d_in[9];
    const float* w1 = (const float*)d_in[10];
    const float* b1 = (const float*)d_in[11];
    const float* w2 = (const float*)d_in[12];
    const float* b2 = (const float*)d_in[13];
    const float* g1  = (const float*)d_in[14];
    const float* be1 = (const float*)d_in[15];
    const float* g2  = (const float*)d_in[16];
    const float* be2 = (const float*)d_in[17];
    float* out = (float*)d_out;

    char* ws = (char*)d_ws;
    const size_t MiB = 1024 * 1024;
    ushort* xn_h = (ushort*)(ws);                 // 8 MiB
    ushort* xn_l = (ushort*)(ws + 8 * MiB);       // 8 MiB
    ushort* q_h  = (ushort*)(ws + 16 * MiB);      // 8 MiB
    ushort* q_l  = (ushort*)(ws + 24 * MiB);      // 8 MiB
    ushort* k_h  = (ushort*)(ws + 32 * MiB);      // 8 MiB
    ushort* k_l  = (ushort*)(ws + 40 * MiB);      // 8 MiB
    ushort* v_h  = (ushort*)(ws + 48 * MiB);      // 8 MiB
    ushort* v_t  = (ushort*)(ws + 56 * MiB);      // 8 MiB
    ushort* wqkvt_h = (ushort*)(ws + 64 * MiB);   // 1.5 MiB (dead after qkv)
    ushort* wqkvt_l = (ushort*)(ws + 66 * MiB);   // 1 MiB  (dead after qkv)
    ushort* wot_h = (ushort*)(ws + 67 * MiB);     // 512 KiB
    unsigned char* mflag = (unsigned char*)(ws + 67 * MiB + 512 * 1024); // 64 KiB
    ushort* w1t_h = (ushort*)(ws + 68 * MiB);     // 2 MiB
    ushort* w2t_h = (ushort*)(ws + 70 * MiB);     // 2 MiB
    ushort* mb    = (ushort*)(ws + 72 * MiB);     // 8 MiB
    ushort* pctx0 = (ushort*)(ws + 80 * MiB);     // 8 MiB
    ushort* pctx1 = (ushort*)(ws + 88 * MiB);     // 8 MiB
    float2* ml    = (float2*)(ws + 64 * MiB);     // 1 MiB, overlays wqkvt_h (dead)
    // overlays
    ushort* ctx  = xn_h;                          // after qkv
    ushort* xn2  = xn_l;                          // after qkv
    ushort* ff1  = q_h;                           // over q,k (dead post-attn)

    dim3 blk256(256);
    wconv4<<<dim3(8, 8, 4), blk256, 0, stream>>>(
        wq, wk, wv, wo, wqkvt_h, wqkvt_l, wqkvt_h + 512 * 512,
        wqkvt_l + 512 * 512, wqkvt_h + 1024 * 512, wot_h);
    wconv<<<dim3(8, 32), blk256, 0, stream>>>(w1, w1t_h, DM, DFF);
    wconv<<<dim3(32, 8), blk256, 0, stream>>>(w2, w2t_h, DFF, DM);
    maskprep<<<SEQ, 64, 0, stream>>>(mask, mb, mflag);
    ln_kernel<true><<<NROWS, 64, 0, stream>>>(x, g1, be1, xn_h, xn_l);
    qkv_gemm<<<dim3(12, NROWS / 128), blk256, 0, stream>>>(
        xn_h, xn_l, wqkvt_h, wqkvt_l, bq, bk, bv, q_h, q_l, k_h, k_l, v_h);
    vtrans<<<dim3(SEQ / 64, 4 * NH), blk256, 0, stream>>>(v_h, v_t);
    {
        dim3 grid(32, 32);  // 1024 blocks: 32 bh x (2 parts x 16 qb)
        attn_kernel<<<grid, blk256, 0, stream>>>(
            q_h, q_l, k_h, k_l, v_t, mb, mflag, pctx0, pctx1, ml);
    }
    attn_combine<<<32 * SEQ * 8 / 256, blk256, 0, stream>>>(pctx0, pctx1, ml, ctx);
    {
        dim3 grid(DM / 128, NROWS / 128);
        mgemm<false,true,0><<<grid, blk256, 0, stream>>>(
            ctx, wot_h, bo, x, out, nullptr, NROWS, DM, DM);
    }
    ln_kernel<false><<<NROWS, 64, 0, stream>>>(out, g2, be2, xn2, nullptr);
    {
        dim3 grid(DFF / 128, NROWS / 128);
        mgemm<true,false,1><<<grid, blk256, 0, stream>>>(
            xn2, w1t_h, b1, nullptr, nullptr, ff1, NROWS, DFF, DM);
    }
    {
        dim3 grid(DM / 128, NROWS / 128);
        mgemm<false,true,0><<<grid, blk256, 0, stream>>>(
            ff1, w2t_h, b2, out, out, nullptr, NROWS, DM, DFF);
    }
}

// Round 9
// 247.856 us; speedup vs baseline: 1.4418x; 1.4418x over previous
//
#include <hip/hip_runtime.h>
#include <cmath>

#define SEQ 2048
#define DM 512
#define DFF 2048
#define NH 8
#define DKH 64
#define NROWS 8192  // B*S = 4*2048

typedef __attribute__((ext_vector_type(8))) short bf16x8;
typedef __attribute__((ext_vector_type(16))) float f32x16;

__device__ __forceinline__ ushort f2bf(float f) {
    uint u = __float_as_uint(f);
    u += 0x7fff + ((u >> 16) & 1);
    return (ushort)(u >> 16);
}
__device__ __forceinline__ float bf2f(ushort h) {
    return __uint_as_float(((uint)h) << 16);
}
__device__ __forceinline__ uint cvtpk_bf16(float a, float b) {
    uint r;
    asm("v_cvt_pk_bf16_f32 %0, %1, %2" : "=v"(r) : "v"(a), "v"(b));
    return r;
}
// async global->LDS, 16B per lane. LDS dest = base + lane*16 (linear).
__device__ __forceinline__ void gl_lds16(const void* g, void* l) {
    __builtin_amdgcn_global_load_lds(
        (const __attribute__((address_space(1))) void*)g,
        (__attribute__((address_space(3))) void*)l, 16, 0, 0);
}
// 128B-row LDS swizzle (attn): byte ^= (row&7)<<4
__device__ __forceinline__ void* swz(char* base, int row, int col) {
    int byte = (row << 7) + (col << 1);
    byte ^= (row & 7) << 4;
    return base + byte;
}
// gemm LDS swizzle: byte ^= ((row>>2)&7)<<4
__device__ __forceinline__ void* swzg(char* base, int row, int k) {
    int byte = (row << 7) + (k << 1);
    byte ^= ((row >> 2) & 7) << 4;
    return base + byte;
}

// ---------------------------------------------------------------------------
// LayerNorm -> bf16 (hi, optional lo)
// ---------------------------------------------------------------------------
template<bool SPLIT>
__global__ __launch_bounds__(64) void ln_kernel(const float* __restrict__ x,
        const float* __restrict__ g, const float* __restrict__ b,
        ushort* __restrict__ oh, ushort* __restrict__ ol) {
    int row = blockIdx.x;
    int t = threadIdx.x;
    const float* xr = x + (size_t)row * DM + t * 8;
    float v[8];
    *(float4*)&v[0] = *(const float4*)(xr);
    *(float4*)&v[4] = *(const float4*)(xr + 4);
    float s = 0.f;
    #pragma unroll
    for (int j = 0; j < 8; ++j) s += v[j];
    #pragma unroll
    for (int m = 32; m > 0; m >>= 1) s += __shfl_xor(s, m);
    float mean = s * (1.0f / DM);
    float ss = 0.f;
    #pragma unroll
    for (int j = 0; j < 8; ++j) { float d = v[j] - mean; ss += d * d; }
    #pragma unroll
    for (int m = 32; m > 0; m >>= 1) ss += __shfl_xor(ss, m);
    float inv = 1.0f / (sqrtf(ss * (1.0f / (DM - 1))) + 1e-6f);
    float gv[8], bv[8];
    *(float4*)&gv[0] = *(const float4*)(g + t * 8);
    *(float4*)&gv[4] = *(const float4*)(g + t * 8 + 4);
    *(float4*)&bv[0] = *(const float4*)(b + t * 8);
    *(float4*)&bv[4] = *(const float4*)(b + t * 8 + 4);
    union { ushort us[8]; float4 f4; } ph, pl;
    #pragma unroll
    for (int j = 0; j < 8; ++j) {
        float o = gv[j] * (v[j] - mean) * inv + bv[j];
        ushort hb = f2bf(o);
        ph.us[j] = hb;
        if (SPLIT) pl.us[j] = f2bf(o - bf2f(hb));
    }
    *(float4*)(oh + (size_t)row * DM + t * 8) = ph.f4;
    if (SPLIT) *(float4*)(ol + (size_t)row * DM + t * 8) = pl.f4;
}

// ---------------------------------------------------------------------------
// Merged weight transpose+convert for the four 512x512 weights.
// ---------------------------------------------------------------------------
__global__ __launch_bounds__(256) void wconv4(
        const float* __restrict__ wq, const float* __restrict__ wk,
        const float* __restrict__ wv, const float* __restrict__ wo,
        ushort* __restrict__ qh, ushort* __restrict__ ql,
        ushort* __restrict__ kh, ushort* __restrict__ kl,
        ushort* __restrict__ vh, ushort* __restrict__ oh) {
    const int K = DM, N = DM;
    __shared__ float tile[64][65];
    int z = blockIdx.z;
    const float* W = (z == 0) ? wq : (z == 1) ? wk : (z == 2) ? wv : wo;
    ushort* Th = (z == 0) ? qh : (z == 1) ? kh : (z == 2) ? vh : oh;
    ushort* Tl = (z == 0) ? ql : (z == 1) ? kl : nullptr;
    bool split = (z < 2);
    int k0 = blockIdx.x * 64, n0 = blockIdx.y * 64;
    int t = threadIdx.x;
    {
        int kr = t >> 2, c0 = (t & 3) * 16;
        const float* src = W + (size_t)(k0 + kr) * N + n0 + c0;
        #pragma unroll
        for (int j = 0; j < 4; ++j)
            *(float4*)&tile[kr][c0 + j * 4] = *(const float4*)(src + j * 4);
    }
    __syncthreads();
    int n = t >> 2, kc = (t & 3) * 16;
    union { ushort us[16]; float4 f4[2]; } ph, pl;
    #pragma unroll
    for (int j = 0; j < 16; ++j) {
        float v = tile[kc + j][n];
        ushort hb = f2bf(v);
        ph.us[j] = hb;
        pl.us[j] = f2bf(v - bf2f(hb));
    }
    ushort* dh = Th + (size_t)(n0 + n) * K + k0 + kc;
    *(float4*)(dh) = ph.f4[0];
    *(float4*)(dh + 8) = ph.f4[1];
    if (split) {
        ushort* dl = Tl + (size_t)(n0 + n) * K + k0 + kc;
        *(float4*)(dl) = pl.f4[0];
        *(float4*)(dl + 8) = pl.f4[1];
    }
}

// ---------------------------------------------------------------------------
// Weight transpose+convert (single, for w1/w2)
// ---------------------------------------------------------------------------
__global__ __launch_bounds__(256) void wconv(const float* __restrict__ W,
        ushort* __restrict__ Th, int K, int N) {
    __shared__ float tile[64][65];
    int k0 = blockIdx.x * 64, n0 = blockIdx.y * 64;
    int t = threadIdx.x;
    {
        int kr = t >> 2, c0 = (t & 3) * 16;
        const float* src = W + (size_t)(k0 + kr) * N + n0 + c0;
        #pragma unroll
        for (int j = 0; j < 4; ++j)
            *(float4*)&tile[kr][c0 + j * 4] = *(const float4*)(src + j * 4);
    }
    __syncthreads();
    int n = t >> 2, kc = (t & 3) * 16;
    union { ushort us[16]; float4 f4[2]; } ph;
    #pragma unroll
    for (int j = 0; j < 16; ++j) ph.us[j] = f2bf(tile[kc + j][n]);
    ushort* dh = Th + (size_t)(n0 + n) * K + k0 + kc;
    *(float4*)(dh) = ph.f4[0];
    *(float4*)(dh + 8) = ph.f4[1];
}

// ---------------------------------------------------------------------------
// V transpose: vh[(b*SEQ+s)][DM] bf16 (head h cols) -> vt[(bh*64+d)][SEQ] bf16
// ---------------------------------------------------------------------------
__global__ __launch_bounds__(256) void vtrans(const ushort* __restrict__ vh,
        ushort* __restrict__ vt) {
    __shared__ __align__(16) char tile[8192];
    int s0 = blockIdx.x * 64;
    int bh = blockIdx.y;
    int b = bh >> 3, h = bh & 7;
    int t = threadIdx.x;
    {
        int r = t >> 2, co = (t & 3) * 16;
        const ushort* src = vh + (size_t)(b * SEQ + s0 + r) * DM + h * DKH + co;
        *(float4*)swz(tile, r, co) = *(const float4*)(src);
        *(float4*)swz(tile, r, co + 8) = *(const float4*)(src + 8);
    }
    __syncthreads();
    int d = t >> 2, j0 = (t & 3) * 16;
    union { ushort us[16]; float4 f4[2]; } o;
    #pragma unroll
    for (int j = 0; j < 16; ++j)
        o.us[j] = *(ushort*)swz(tile, j0 + j, d);
    ushort* dst = vt + ((size_t)bh * DKH + d) * SEQ + s0 + j0;
    *(float4*)(dst) = o.f4[0];
    *(float4*)(dst + 8) = o.f4[1];
}

// ---------------------------------------------------------------------------
// Mask -> additive bf16 bias {0,-1e9} + per-(row, 64-key-tile) all-ones flags.
// ---------------------------------------------------------------------------
__global__ __launch_bounds__(64) void maskprep(const int* __restrict__ mask,
        ushort* __restrict__ mb, unsigned char* __restrict__ mflag) {
    int row = blockIdx.x;
    int lane = threadIdx.x;
    ushort neg = f2bf(-1e9f);
    unsigned long long bal[4];
    #pragma unroll
    for (int u = 0; u < 4; ++u) {
        int base = row * SEQ + u * 512 + lane * 8;
        int4 a = *(const int4*)(mask + base);
        int4 c = *(const int4*)(mask + base + 4);
        union { ushort us[8]; float4 f4; } o;
        o.us[0] = a.x ? (ushort)0 : neg;
        o.us[1] = a.y ? (ushort)0 : neg;
        o.us[2] = a.z ? (ushort)0 : neg;
        o.us[3] = a.w ? (ushort)0 : neg;
        o.us[4] = c.x ? (ushort)0 : neg;
        o.us[5] = c.y ? (ushort)0 : neg;
        o.us[6] = c.z ? (ushort)0 : neg;
        o.us[7] = c.w ? (ushort)0 : neg;
        *(float4*)(mb + base) = o.f4;
        bool ok = a.x && a.y && a.z && a.w && c.x && c.y && c.z && c.w;
        bal[u] = __ballot(ok);
    }
    if (lane < 32) {
        int u = lane >> 3;
        unsigned long long bsel = bal[0];
        bsel = (u == 1) ? bal[1] : bsel;
        bsel = (u == 2) ? bal[2] : bsel;
        bsel = (u == 3) ? bal[3] : bsel;
        int byte = (int)((bsel >> ((lane & 7) * 8)) & 0xFFull);
        mflag[row * 32 + lane] = (byte == 0xFF) ? 1 : 0;
    }
}

// ---------------------------------------------------------------------------
// 1-term MFMA GEMM, double-buffered via global_load_lds prefetch.
// ---------------------------------------------------------------------------
template<bool RELU, bool HASRES, int OUT>
__global__ __launch_bounds__(256) void mgemm(
        const ushort* __restrict__ Ah, const ushort* __restrict__ Bth,
        const float* __restrict__ bias, const float* __restrict__ resid,
        float* __restrict__ Cf, ushort* __restrict__ Cbh,
        int M, int N, int K) {
    __shared__ __align__(16) char smem[65536];
    int tid = threadIdx.x;
    int lane = tid & 63, w = tid >> 6;
    int ln31 = lane & 31, hi = lane >> 5;
    int mh = (w >> 1) * 64, nh = (w & 1) * 64;
    int gx = gridDim.x;
    int nwg = gx * gridDim.y;
    int flat = blockIdx.y * gx + blockIdx.x;
    int sid = (flat & 7) * (nwg >> 3) + (flat >> 3);
    int n0 = (sid % gx) * 128;
    int m0 = (sid / gx) * 128;

    f32x16 acc[2][2];
    #pragma unroll
    for (int i = 0; i < 2; ++i)
        #pragma unroll
        for (int j = 0; j < 2; ++j)
            #pragma unroll
            for (int r = 0; r < 16; ++r) acc[i][j][r] = 0.f;

    auto stage = [&](char* Abuf, char* Bbuf, int k0) {
        #pragma unroll
        for (int c = 0; c < 4; ++c) {
            int ch = w * 4 + c;
            int r = ch * 8 + (lane >> 3);
            int u = (lane & 7) ^ ((r >> 2) & 7);
            gl_lds16(Ah + (size_t)(m0 + r) * K + k0 + u * 8, Abuf + ch * 1024);
            gl_lds16(Bth + (size_t)(n0 + r) * K + k0 + u * 8, Bbuf + ch * 1024);
        }
    };

    char* A0 = smem;
    char* B0 = smem + 16384;
    char* A1 = smem + 32768;
    char* B1 = smem + 49152;

    stage(A0, B0, 0);
    __syncthreads();
    int nk = K / 64;
    for (int kt = 0; kt < nk; ++kt) {
        char* Ac = (kt & 1) ? A1 : A0;
        char* Bc = (kt & 1) ? B1 : B0;
        if (kt + 1 < nk)
            stage((kt & 1) ? A0 : A1, (kt & 1) ? B0 : B1, (kt + 1) * 64);
        __builtin_amdgcn_s_setprio(1);
        #pragma unroll
        for (int km = 0; km < 4; ++km) {
            int kk = km * 16 + hi * 8;
            bf16x8 ah[2], bh[2];
            ah[0] = *(bf16x8*)swzg(Ac, mh + ln31, kk);
            ah[1] = *(bf16x8*)swzg(Ac, mh + 32 + ln31, kk);
            bh[0] = *(bf16x8*)swzg(Bc, nh + ln31, kk);
            bh[1] = *(bf16x8*)swzg(Bc, nh + 32 + ln31, kk);
            #pragma unroll
            for (int mi = 0; mi < 2; ++mi)
                #pragma unroll
                for (int ni = 0; ni < 2; ++ni)
                    acc[mi][ni] = __builtin_amdgcn_mfma_f32_32x32x16_bf16(
                        ah[mi], bh[ni], acc[mi][ni], 0, 0, 0);
        }
        __builtin_amdgcn_s_setprio(0);
        __syncthreads();
    }
    float bv[2];
    bv[0] = bias[n0 + nh + ln31];
    bv[1] = bias[n0 + nh + 32 + ln31];
    #pragma unroll
    for (int mi = 0; mi < 2; ++mi)
        #pragma unroll
        for (int ni = 0; ni < 2; ++ni) {
            int n = n0 + nh + ni * 32 + ln31;
            #pragma unroll
            for (int r = 0; r < 16; ++r) {
                int m = m0 + mh + mi * 32 + (r & 3) + 8 * (r >> 2) + 4 * hi;
                float v = acc[mi][ni][r] + bv[ni];
                if (HASRES) v += resid[(size_t)m * N + n];
                if (RELU) v = fmaxf(v, 0.f);
                size_t idx = (size_t)m * N + n;
                if (OUT == 0) Cf[idx] = v;
                else Cbh[idx] = f2bf(v);
            }
        }
}

// ---------------------------------------------------------------------------
// Fused QKV GEMM. Q output pre-scaled by 1/8 (exact exponent shift).
// ---------------------------------------------------------------------------
__global__ __launch_bounds__(256) void qkv_gemm(
        const ushort* __restrict__ Ah, const ushort* __restrict__ Al,
        const ushort* __restrict__ Bth, const ushort* __restrict__ Btl,
        const float* __restrict__ bq, const float* __restrict__ bk,
        const float* __restrict__ bv_, ushort* __restrict__ q_h,
        ushort* __restrict__ q_l, ushort* __restrict__ k_h,
        ushort* __restrict__ k_l, ushort* __restrict__ v_h) {
    const int K = DM, N = DM;
    __shared__ __align__(16) char smem[65536];
    char* As_h = smem;
    char* Bs_h = smem + 16384;
    char* As_l = smem + 32768;
    char* Bs_l = smem + 49152;
    int tid = threadIdx.x;
    int lane = tid & 63, w = tid >> 6;
    int ln31 = lane & 31, hi = lane >> 5;
    int mh = (w >> 1) * 64, nh = (w & 1) * 64;
    int gx = gridDim.x;  // 12
    int nwg = gx * gridDim.y;
    int flat = blockIdx.y * gx + blockIdx.x;
    int sid = (flat & 7) * (nwg >> 3) + (flat >> 3);
    int n0 = (sid % gx) * 128;
    int m0 = (sid / gx) * 128;
    bool isqk = (n0 < 1024);

    f32x16 acc[2][2];
    #pragma unroll
    for (int i = 0; i < 2; ++i)
        #pragma unroll
        for (int j = 0; j < 2; ++j)
            #pragma unroll
            for (int r = 0; r < 16; ++r) acc[i][j][r] = 0.f;

    for (int k0 = 0; k0 < K; k0 += 64) {
        #pragma unroll
        for (int c = 0; c < 4; ++c) {
            int ch = w * 4 + c;
            int r = ch * 8 + (lane >> 3);
            int u = (lane & 7) ^ ((r >> 2) & 7);
            gl_lds16(Ah + (size_t)(m0 + r) * K + k0 + u * 8, As_h + ch * 1024);
            gl_lds16(Bth + (size_t)(n0 + r) * K + k0 + u * 8, Bs_h + ch * 1024);
            if (isqk) {
                gl_lds16(Al + (size_t)(m0 + r) * K + k0 + u * 8, As_l + ch * 1024);
                gl_lds16(Btl + (size_t)(n0 + r) * K + k0 + u * 8, Bs_l + ch * 1024);
            }
        }
        __syncthreads();
        __builtin_amdgcn_s_setprio(1);
        #pragma unroll
        for (int km = 0; km < 4; ++km) {
            int kk = km * 16 + hi * 8;
            bf16x8 ah[2], bh[2];
            ah[0] = *(bf16x8*)swzg(As_h, mh + ln31, kk);
            ah[1] = *(bf16x8*)swzg(As_h, mh + 32 + ln31, kk);
            bh[0] = *(bf16x8*)swzg(Bs_h, nh + ln31, kk);
            bh[1] = *(bf16x8*)swzg(Bs_h, nh + 32 + ln31, kk);
            if (isqk) {
                bf16x8 al[2], bl[2];
                al[0] = *(bf16x8*)swzg(As_l, mh + ln31, kk);
                al[1] = *(bf16x8*)swzg(As_l, mh + 32 + ln31, kk);
                bl[0] = *(bf16x8*)swzg(Bs_l, nh + ln31, kk);
                bl[1] = *(bf16x8*)swzg(Bs_l, nh + 32 + ln31, kk);
                #pragma unroll
                for (int mi = 0; mi < 2; ++mi)
                    #pragma unroll
                    for (int ni = 0; ni < 2; ++ni) {
                        acc[mi][ni] = __builtin_amdgcn_mfma_f32_32x32x16_bf16(
                            ah[mi], bh[ni], acc[mi][ni], 0, 0, 0);
                        acc[mi][ni] = __builtin_amdgcn_mfma_f32_32x32x16_bf16(
                            ah[mi], bl[ni], acc[mi][ni], 0, 0, 0);
                        acc[mi][ni] = __builtin_amdgcn_mfma_f32_32x32x16_bf16(
                            al[mi], bh[ni], acc[mi][ni], 0, 0, 0);
                    }
            } else {
                #pragma unroll
                for (int mi = 0; mi < 2; ++mi)
                    #pragma unroll
                    for (int ni = 0; ni < 2; ++ni)
                        acc[mi][ni] = __builtin_amdgcn_mfma_f32_32x32x16_bf16(
                            ah[mi], bh[ni], acc[mi][ni], 0, 0, 0);
            }
        }
        __builtin_amdgcn_s_setprio(0);
        __syncthreads();
    }
    const float* bias = (n0 < 512) ? bq : (n0 < 1024 ? bk : bv_);
    int ncol0 = n0 & 511;
    ushort* Oh = (n0 < 512) ? q_h : (n0 < 1024 ? k_h : v_h);
    ushort* Ol = (n0 < 512) ? q_l : (n0 < 1024 ? k_l : nullptr);
    float scale = (n0 < 512) ? 0.125f : 1.0f;
    float bvv[2];
    bvv[0] = bias[ncol0 + nh + ln31];
    bvv[1] = bias[ncol0 + nh + 32 + ln31];
    #pragma unroll
    for (int mi = 0; mi < 2; ++mi)
        #pragma unroll
        for (int ni = 0; ni < 2; ++ni) {
            int n = ncol0 + nh + ni * 32 + ln31;
            #pragma unroll
            for (int r = 0; r < 16; ++r) {
                int m = m0 + mh + mi * 32 + (r & 3) + 8 * (r >> 2) + 4 * hi;
                float v = (acc[mi][ni][r] + bvv[ni]) * scale;
                size_t idx = (size_t)m * N + n;
                ushort hb = f2bf(v);
                Oh[idx] = hb;
                if (isqk) Ol[idx] = f2bf(v - bf2f(hb));
            }
        }
}

// ---------------------------------------------------------------------------
// MFMA flash attention, split-K x2. 40KB LDS (4 blocks/CU by LDS):
// K hi/lo double-buffered (2x16K), V^T single-buffered (8K).
// Per-ksub softmax (R7 register footprint, ~84 VGPR, no spill).
// Schedule per kt: stage_K(kt+1); QK0+softmax0; barrier(drain V(kt),K(kt+1));
// PV0; QK1+softmax1+PV1; barrier; stage_V(kt+1).
// ---------------------------------------------------------------------------
__global__ __launch_bounds__(256, 3) void attn_kernel(
        const ushort* __restrict__ Qh, const ushort* __restrict__ Ql,
        const ushort* __restrict__ Khg, const ushort* __restrict__ Klg,
        const ushort* __restrict__ Vtg, const ushort* __restrict__ mb,
        const unsigned char* __restrict__ mflag,
        ushort* __restrict__ pctx0, ushort* __restrict__ pctx1,
        float2* __restrict__ ml) {
    __shared__ __align__(16) char smem[40960];
    // K buf0 @0 (Kh 8K + Kl 8K), K buf1 @16K, Vt @32K (8K)
    int tid = threadIdx.x;
    int w = tid >> 6, lane = tid & 63;
    int ln31 = lane & 31, hi = lane >> 5;
    bool hib = (hi != 0);
    int f = blockIdx.y * gridDim.x + blockIdx.x;
    int g = (f & 7) * 128 + (f >> 3);
    int bh = g >> 5, rest = g & 31;
    int part = rest >> 4, qb = rest & 15;
    int b = bh >> 3, h = bh & 7;
    int q0 = qb * 128;
    size_t brow = (size_t)b * SEQ;
    int hcol = h * DKH;
    int ktbeg = part * 16, ktend = ktbeg + 16;

    auto stage_K = [&](int kt) {
        char* buf = smem + (kt & 1) * 16384;
        #pragma unroll
        for (int c = 0; c < 2; ++c) {
            int ch = w * 2 + c;
            int r = ch * 8 + (lane >> 3);
            int u = (lane & 7) ^ (r & 7);
            gl_lds16(Khg + (brow + kt * 64 + r) * DM + hcol + u * 8,
                     buf + ch * 1024);
            gl_lds16(Klg + (brow + kt * 64 + r) * DM + hcol + u * 8,
                     buf + 8192 + ch * 1024);
        }
    };
    auto stage_V = [&](int kt) {
        char* buf = smem + 32768;
        #pragma unroll
        for (int c = 0; c < 2; ++c) {
            int ch = w * 2 + c;
            int r = ch * 8 + (lane >> 3);
            int u = (lane & 7) ^ (r & 7);
            gl_lds16(Vtg + ((size_t)bh * DKH + r) * SEQ + kt * 64 + u * 8,
                     buf + ch * 1024);
        }
    };

    // prologue: stage Q into smem[0..32K), read frags
    {
        char* QhL = smem;
        char* QlL = smem + 16384;
        #pragma unroll
        for (int c = 0; c < 4; ++c) {
            int ch = w * 4 + c;
            int r = ch * 8 + (lane >> 3);
            int u = (lane & 7) ^ (r & 7);
            gl_lds16(Qh + (brow + q0 + r) * DM + hcol + u * 8, QhL + ch * 1024);
            gl_lds16(Ql + (brow + q0 + r) * DM + hcol + u * 8, QlL + ch * 1024);
        }
    }
    __syncthreads();
    bf16x8 qfh[4], qfl[4];
    {
        int qr = w * 32 + ln31;
        #pragma unroll
        for (int c = 0; c < 4; ++c) {
            qfh[c] = *(bf16x8*)swz(smem, qr, c * 16 + hi * 8);
            qfl[c] = *(bf16x8*)swz(smem + 16384, qr, c * 16 + hi * 8);
        }
    }
    __syncthreads();  // Q region reusable as K buffers
    stage_K(ktbeg);
    stage_V(ktbeg);
    __syncthreads();  // drains first K/V

    f32x16 ctx0, ctx1;
    #pragma unroll
    for (int r = 0; r < 16; ++r) { ctx0[r] = 0.f; ctx1[r] = 0.f; }
    float m_i = -1e30f, l_i = 0.f;
    int qglob = q0 + w * 32 + ln31;
    const ushort* mrow = mb + (size_t)qglob * SEQ;

    for (int kt = ktbeg; kt < ktend; ++kt) {
        if (kt + 1 < ktend) stage_K(kt + 1);
        char* KhL = smem + (kt & 1) * 16384;
        char* KlL = KhL + 8192;
        char* VtL = smem + 32768;
        unsigned char fl = mflag[qglob * 32 + kt];
        bool domask = !__all(fl != 0);
        ushort4 mpre[8];
        if (domask) {
            #pragma unroll
            for (int i = 0; i < 8; ++i)
                mpre[i] = *(const ushort4*)(mrow + kt * 64 + i * 8 + hi * 4);
        }
        #pragma unroll
        for (int ksub = 0; ksub < 2; ++ksub) {
            // ---- QK^T (Q pre-scaled by 1/8) ----
            f32x16 s;
            #pragma unroll
            for (int r = 0; r < 16; ++r) s[r] = 0.f;
            __builtin_amdgcn_s_setprio(1);
            #pragma unroll
            for (int c = 0; c < 4; ++c) {
                bf16x8 ka = *(bf16x8*)swz(KhL, ksub * 32 + ln31, c * 16 + hi * 8);
                bf16x8 kb = *(bf16x8*)swz(KlL, ksub * 32 + ln31, c * 16 + hi * 8);
                s = __builtin_amdgcn_mfma_f32_32x32x16_bf16(ka, qfh[c], s, 0, 0, 0);
                s = __builtin_amdgcn_mfma_f32_32x32x16_bf16(ka, qfl[c], s, 0, 0, 0);
                s = __builtin_amdgcn_mfma_f32_32x32x16_bf16(kb, qfh[c], s, 0, 0, 0);
            }
            __builtin_amdgcn_s_setprio(0);
            // ---- floor + mask + online softmax ----
            float tmax = -1e30f;
            if (domask) {
                #pragma unroll
                for (int rg = 0; rg < 4; ++rg) {
                    ushort4 mv = mpre[ksub * 4 + rg];
                    ushort mu[4] = {mv.x, mv.y, mv.z, mv.w};
                    #pragma unroll
                    for (int j = 0; j < 4; ++j) {
                        int r = rg * 4 + j;
                        float sc = floorf(s[r]) + bf2f(mu[j]);
                        s[r] = sc;
                        tmax = fmaxf(tmax, sc);
                    }
                }
            } else {
                #pragma unroll
                for (int r = 0; r < 16; ++r) {
                    float sc = floorf(s[r]);
                    s[r] = sc;
                    tmax = fmaxf(tmax, sc);
                }
            }
            tmax = fmaxf(tmax, __shfl_xor(tmax, 32));
            if (!__all(tmax <= m_i)) {
                float newm = fmaxf(m_i, tmax);
                float scl = __expf(m_i - newm);
                m_i = newm;
                l_i *= scl;
                #pragma unroll
                for (int r = 0; r < 16; ++r) { ctx0[r] *= scl; ctx1[r] *= scl; }
            }
            float psum = 0.f;
            #pragma unroll
            for (int r = 0; r < 16; ++r) {
                float p = __expf(s[r] - m_i);
                s[r] = p;
                psum += p;
            }
            psum += __shfl_xor(psum, 32);
            l_i += psum;
            // ---- pack P and exchange across hi-halves in-reg ----
            uint pk0[4], pk1[4];
            #pragma unroll
            for (int rg = 0; rg < 4; ++rg) {
                pk0[rg] = cvtpk_bf16(s[rg * 4 + 0], s[rg * 4 + 1]);
                pk1[rg] = cvtpk_bf16(s[rg * 4 + 2], s[rg * 4 + 3]);
            }
            bf16x8 pb[2];
            #pragma unroll
            for (int cc = 0; cc < 2; ++cc) {
                uint A0 = pk0[cc * 2], A1 = pk1[cc * 2];
                uint B0 = pk0[cc * 2 + 1], B1 = pk1[cc * 2 + 1];
                uint send0 = hib ? A0 : B0;
                uint send1 = hib ? A1 : B1;
                uint own0  = hib ? B0 : A0;
                uint own1  = hib ? B1 : A1;
                uint recv0 = (uint)__shfl_xor((int)send0, 32);
                uint recv1 = (uint)__shfl_xor((int)send1, 32);
                union { uint u[4]; bf16x8 v; } pbu;
                pbu.u[0] = hib ? recv0 : own0;
                pbu.u[1] = hib ? recv1 : own1;
                pbu.u[2] = hib ? own0 : recv0;
                pbu.u[3] = hib ? own1 : recv1;
                pb[cc] = pbu.v;
            }
            // barrier once per tile, before first PV: drains V(kt) (issued
            // end of prev iter) and K(kt+1) (issued top of this iter).
            if (ksub == 0) __syncthreads();
            // ---- PV ----
            __builtin_amdgcn_s_setprio(1);
            #pragma unroll
            for (int cc = 0; cc < 2; ++cc) {
                int c = ksub * 2 + cc;
                bf16x8 va0 = *(bf16x8*)swz(VtL, ln31, c * 16 + hi * 8);
                bf16x8 va1 = *(bf16x8*)swz(VtL, 32 + ln31, c * 16 + hi * 8);
                ctx0 = __builtin_amdgcn_mfma_f32_32x32x16_bf16(va0, pb[cc], ctx0, 0, 0, 0);
                ctx1 = __builtin_amdgcn_mfma_f32_32x32x16_bf16(va1, pb[cc], ctx1, 0, 0, 0);
            }
            __builtin_amdgcn_s_setprio(0);
        }
        __syncthreads();  // all waves done reading Vt (and K(kt))
        if (kt + 1 < ktend) stage_V(kt + 1);
    }

    // epilogue: write unnormalized partial ctx (bf16) + (m,l)
    ushort* P = part ? pctx1 : pctx0;
    size_t pbase = ((size_t)bh * SEQ + qglob) * DKH;
    #pragma unroll
    for (int r = 0; r < 16; ++r) {
        int d = (r & 3) + 8 * (r >> 2) + 4 * hi;
        P[pbase + d] = f2bf(ctx0[r]);
        P[pbase + 32 + d] = f2bf(ctx1[r]);
    }
    if (hi == 0)
        ml[((size_t)part * 32 + bh) * SEQ + qglob] = make_float2(m_i, l_i);
}

// ---------------------------------------------------------------------------
// Combine the two split-K partials exactly; write ctx bf16 [b*SEQ+q][DM].
// ---------------------------------------------------------------------------
__global__ __launch_bounds__(256) void attn_combine(
        const ushort* __restrict__ p0, const ushort* __restrict__ p1,
        const float2* __restrict__ ml, ushort* __restrict__ O) {
    int idx = blockIdx.x * 256 + threadIdx.x;
    int d0 = (idx & 7) * 8;
    int q = (idx >> 3) & (SEQ - 1);
    int bh = idx >> 14;
    int b = bh >> 3, h = bh & 7;
    size_t pb = ((size_t)bh * SEQ + q) * DKH + d0;
    bf16x8 c0 = *(const bf16x8*)(p0 + pb);
    bf16x8 c1 = *(const bf16x8*)(p1 + pb);
    float2 e0 = ml[(size_t)bh * SEQ + q];
    float2 e1 = ml[((size_t)32 + bh) * SEQ + q];
    float m = fmaxf(e0.x, e1.x);
    float w0 = __expf(e0.x - m), w1 = __expf(e1.x - m);
    float inv = 1.0f / (e0.y * w0 + e1.y * w1);
    union { ushort us[8]; float4 f4; } o;
    #pragma unroll
    for (int j = 0; j < 8; ++j) {
        float v0 = bf2f((ushort)c0[j]);
        float v1 = bf2f((ushort)c1[j]);
        o.us[j] = f2bf((v0 * w0 + v1 * w1) * inv);
    }
    *(float4*)(O + ((size_t)(b * SEQ + q)) * DM + h * DKH + d0) = o.f4;
}

// ---------------------------------------------------------------------------
extern "C" void kernel_launch(void* const* d_in, const int* in_sizes, int n_in,
                              void* d_out, int out_size, void* d_ws, size_t ws_size,
                              hipStream_t stream) {
    const float* x    = (const float*)d_in[0];
    const int*   mask = (const int*)d_in[1];
    const float* wq = (const float*)d_in[2];
    const float* bq = (const float*)d_in[3];
    const float* wk = (const float*)d_in[4];
    const float* bk = (const float*)d_in[5];
    const float* wv = (const float*)d_in[6];
    const float* bv = (const float*)d_in[7];
    const float* wo = (const float*)d_in[8];
    const float* bo = (const float*)d_in[9];
    const float* w1 = (const float*)d_in[10];
    const float* b1 = (const float*)d_in[11];
    const float* w2 = (const float*)d_in[12];
    const float* b2 = (const float*)d_in[13];
    const float* g1  = (const float*)d_in[14];
    const float* be1 = (const float*)d_in[15];
    const float* g2  = (const float*)d_in[16];
    const float* be2 = (const float*)d_in[17];
    float* out = (float*)d_out;

    char* ws = (char*)d_ws;
    const size_t MiB = 1024 * 1024;
    ushort* xn_h = (ushort*)(ws);                 // 8 MiB
    ushort* xn_l = (ushort*)(ws + 8 * MiB);       // 8 MiB
    ushort* q_h  = (ushort*)(ws + 16 * MiB);      // 8 MiB
    ushort* q_l  = (ushort*)(ws + 24 * MiB);      // 8 MiB
    ushort* k_h  = (ushort*)(ws + 32 * MiB);      // 8 MiB
    ushort* k_l  = (ushort*)(ws + 40 * MiB);      // 8 MiB
    ushort* v_h  = (ushort*)(ws + 48 * MiB);      // 8 MiB
    ushort* v_t  = (ushort*)(ws + 56 * MiB);      // 8 MiB
    ushort* wqkvt_h = (ushort*)(ws + 64 * MiB);   // 1.5 MiB (dead after qkv)
    ushort* wqkvt_l = (ushort*)(ws + 66 * MiB);   // 1 MiB  (dead after qkv)
    ushort* wot_h = (ushort*)(ws + 67 * MiB);     // 512 KiB
    unsigned char* mflag = (unsigned char*)(ws + 67 * MiB + 512 * 1024); // 64 KiB
    ushort* w1t_h = (ushort*)(ws + 68 * MiB);     // 2 MiB
    ushort* w2t_h = (ushort*)(ws + 70 * MiB);     // 2 MiB
    ushort* mb    = (ushort*)(ws + 72 * MiB);     // 8 MiB
    ushort* pctx0 = (ushort*)(ws + 80 * MiB);     // 8 MiB
    ushort* pctx1 = (ushort*)(ws + 88 * MiB);     // 8 MiB
    float2* ml    = (float2*)(ws + 64 * MiB);     // 1 MiB, overlays wqkvt_h (dead)
    // overlays
    ushort* ctx  = xn_h;                          // after qkv
    ushort* xn2  = xn_l;                          // after qkv
    ushort* ff1  = q_h;                           // over q,k (dead post-attn)

    dim3 blk256(256);
    wconv4<<<dim3(8, 8, 4), blk256, 0, stream>>>(
        wq, wk, wv, wo, wqkvt_h, wqkvt_l, wqkvt_h + 512 * 512,
        wqkvt_l + 512 * 512, wqkvt_h + 1024 * 512, wot_h);
    wconv<<<dim3(8, 32), blk256, 0, stream>>>(w1, w1t_h, DM, DFF);
    wconv<<<dim3(32, 8), blk256, 0, stream>>>(w2, w2t_h, DFF, DM);
    maskprep<<<SEQ, 64, 0, stream>>>(mask, mb, mflag);
    ln_kernel<true><<<NROWS, 64, 0, stream>>>(x, g1, be1, xn_h, xn_l);
    qkv_gemm<<<dim3(12, NROWS / 128), blk256, 0, stream>>>(
        xn_h, xn_l, wqkvt_h, wqkvt_l, bq, bk, bv, q_h, q_l, k_h, k_l, v_h);
    vtrans<<<dim3(SEQ / 64, 4 * NH), blk256, 0, stream>>>(v_h, v_t);
    {
        dim3 grid(32, 32);  // 1024 blocks: 32 bh x (2 parts x 16 qb)
        attn_kernel<<<grid, blk256, 0, stream>>>(
            q_h, q_l, k_h, k_l, v_t, mb, mflag, pctx0, pctx1, ml);
    }
    attn_combine<<<32 * SEQ * 8 / 256, blk256, 0, stream>>>(pctx0, pctx1, ml, ctx);
    {
        dim3 grid(DM / 128, NROWS / 128);
        mgemm<false,true,0><<<grid, blk256, 0, stream>>>(
            ctx, wot_h, bo, x, out, nullptr, NROWS, DM, DM);
    }
    ln_kernel<false><<<NROWS, 64, 0, stream>>>(out, g2, be2, xn2, nullptr);
    {
        dim3 grid(DFF / 128, NROWS / 128);
        mgemm<true,false,1><<<grid, blk256, 0, stream>>>(
            xn2, w1t_h, b1, nullptr, nullptr, ff1, NROWS, DFF, DM);
    }
    {
        dim3 grid(DM / 128, NROWS / 128);
        mgemm<false,true,0><<<grid, blk256, 0, stream>>>(
            ff1, w2t_h, b2, out, out, nullptr, NROWS, DM, DFF);
    }
}